// Round 1
// 364.806 us; speedup vs baseline: 1.0570x; 1.0570x over previous
//
#include <hip/hip_runtime.h>

#define NN 50000
#define EE 800000
#define DD 128
#define CC 64
#define SCAN_B 512
#define NBLK ((NN + SCAN_B - 1) / SCAN_B)   // 98
#define LDA 264    // LDS A row stride in u16: 256 data + 8 pad (2-way bank alias = free)

// bucketed CSR fill
#define BSH 7                                 // 128 dst-nodes per bucket
#define NBKT ((NN + (1 << BSH) - 1) >> BSH)   // 391
#define BCAP 3072                             // mean 2048, sd ~45 -> huge margin
#define EPB 8192                              // edges per bucket-block (1024 thr x 8)

typedef unsigned short u16;
typedef unsigned int u32;
typedef __attribute__((ext_vector_type(8))) short short8;   // 8 bf16
typedef __attribute__((ext_vector_type(4))) float f32x4;

__device__ __forceinline__ float bf2f(u16 u) {
    union { u32 i; float f; } v; v.i = ((u32)u) << 16; return v.f;
}
__device__ __forceinline__ u16 f2bf(float f) {
    union { float f; u32 i; } v; v.f = f;
    u32 x = v.i;
    u32 r = x + 0x7fffu + ((x >> 16) & 1u);   // round-to-nearest-even
    return (u16)(r >> 16);
}

// ---------------- phase A: bucket edges by dst>>7, fold in degree count ----------------
// LDS multisplit: per-block histogram -> one global atomicAdd per bucket -> contiguous
// per-block append runs inside each bucket (~21 pairs = 168B) => mostly-full 64B lines.

__global__ __launch_bounds__(1024) void k_bucket(const int* __restrict__ src,
                                                 const int* __restrict__ dst,
                                                 int* __restrict__ deg,
                                                 int* __restrict__ bcnt,
                                                 uint2* __restrict__ bkt) {
    __shared__ int cnt[NBKT];
    __shared__ int base[NBKT];
    int t = threadIdx.x;
    int e0 = blockIdx.x * EPB;
    for (int i = t; i < NBKT; i += 1024) cnt[i] = 0;
    __syncthreads();
    int d[8], s[8], lp[8];
#pragma unroll
    for (int j = 0; j < 8; ++j) {
        int e = e0 + t + 1024 * j;
        if (e < EE) {
            d[j] = dst[e];
            s[j] = src[e];
            atomicAdd(&deg[d[j]], 1);
            lp[j] = atomicAdd(&cnt[d[j] >> BSH], 1);
        } else {
            d[j] = -1;
        }
    }
    __syncthreads();
    for (int i = t; i < NBKT; i += 1024)
        base[i] = atomicAdd(&bcnt[i], cnt[i]);
    __syncthreads();
#pragma unroll
    for (int j = 0; j < 8; ++j) {
        if (d[j] >= 0) {
            int b = d[j] >> BSH;
            bkt[(size_t)b * BCAP + base[b] + lp[j]] = make_uint2((u32)s[j], (u32)d[j]);
        }
    }
}

// ---------------- 3-phase exclusive scan over deg -> row_off, inv_deg ----------------

__global__ __launch_bounds__(512) void k_bsum(const int* __restrict__ deg,
                                              int* __restrict__ bsum) {
    __shared__ int ws[8];
    int b = blockIdx.x, t = threadIdx.x;
    int i = b * SCAN_B + t;
    int x = (i < NN) ? deg[i] : 0;
#pragma unroll
    for (int o = 1; o < 64; o <<= 1) x += __shfl_xor(x, o);
    if ((t & 63) == 0) ws[t >> 6] = x;
    __syncthreads();
    if (t == 0) {
        int s = 0;
#pragma unroll
        for (int w = 0; w < 8; ++w) s += ws[w];
        bsum[b] = s;
    }
}

__global__ __launch_bounds__(128) void k_bscan(int* __restrict__ bsum,
                                               int* __restrict__ row_off) {
    __shared__ int w0sum;
    int t = threadIdx.x;
    int v = (t < NBLK) ? bsum[t] : 0;
    int x = v;
#pragma unroll
    for (int o = 1; o < 64; o <<= 1) {
        int y = __shfl_up(x, o, 64);
        if ((t & 63) >= o) x += y;
    }
    if (t == 63) w0sum = x;
    __syncthreads();
    if (t >= 64) x += w0sum;
    if (t < NBLK) bsum[t] = x - v;       // exclusive
    if (t == NBLK - 1) row_off[NN] = x;  // total == EE
}

__global__ __launch_bounds__(512) void k_cscan(const int* __restrict__ deg,
                                               const int* __restrict__ bsum,
                                               int* __restrict__ row_off,
                                               float* __restrict__ inv_deg) {
    __shared__ int ws[8];
    int b = blockIdx.x, t = threadIdx.x;
    int i = b * SCAN_B + t;
    int v = (i < NN) ? deg[i] : 0;
    int lane = t & 63, wid = t >> 6;
    int x = v;
#pragma unroll
    for (int o = 1; o < 64; o <<= 1) {
        int y = __shfl_up(x, o, 64);
        if (lane >= o) x += y;
    }
    if (lane == 63) ws[wid] = x;
    __syncthreads();
    int woff = 0;
    for (int w = 0; w < wid; ++w) woff += ws[w];
    if (i < NN) {
        row_off[i] = bsum[b] + woff + x - v;
        inv_deg[i] = 1.0f / fmaxf((float)v, 1.0f);
    }
}

// ---------------- phase B: bucket -> csr. One block per bucket: the bucket's csr
// range (~8KB) is written by exactly one block/XCD => full-line writes, L2-resident.

__global__ __launch_bounds__(256) void k_fill2(const int* __restrict__ bcnt,
                                               const uint2* __restrict__ bkt,
                                               const int* __restrict__ row_off,
                                               int* __restrict__ cursor,
                                               int* __restrict__ csr) {
    int b = blockIdx.x;
    int n = bcnt[b];
    const uint2* bp = bkt + (size_t)b * BCAP;
    for (int i = threadIdx.x; i < n; i += 256) {
        uint2 p = bp[i];
        int d = (int)p.y;
        int pos = atomicAdd(&cursor[d], 1);
        csr[row_off[d] + pos] = (int)p.x;
    }
}

// ---------------- x -> bf16 shadow ----------------

__global__ __launch_bounds__(256) void k_x2bf(const float* __restrict__ x,
                                              u16* __restrict__ xb) {
    int i = (blockIdx.x * 256 + threadIdx.x) * 4;
    if (i < NN * DD) {
        float4 v = *(const float4*)(x + i);
        uint2 p;
        p.x = (u32)f2bf(v.x) | ((u32)f2bf(v.y) << 16);
        p.y = (u32)f2bf(v.z) | ((u32)f2bf(v.w) << 16);
        *(uint2*)(xb + i) = p;
    }
}

// ---------------- weight pack: [Ws;Wn] (256x128) -> MFMA B-fragment order, bf16 ----------------
// frag (ks,nt,lane) holds B[ks*32 + (lane>>4)*8 + j][nt*16 + (lane&15)], j=0..7 contiguous.

__global__ __launch_bounds__(256) void k_wpack(const float* __restrict__ Ws,
                                               const float* __restrict__ Wn,
                                               u16* __restrict__ wpk) {
    int tid = blockIdx.x * 256 + threadIdx.x;   // 3 layers * 4096 frags
    if (tid >= 3 * 4096) return;
    int layer = tid >> 12;
    int rem = tid & 4095;
    int ks = rem >> 9;
    int nt = (rem >> 6) & 7;
    int lane = rem & 63;
    int n = nt * 16 + (lane & 15);
    int kb = ks * 32 + (lane >> 4) * 8;
    u16 o[8];
#pragma unroll
    for (int j = 0; j < 8; ++j) {
        int k = kb + j;
        float w = (k < DD) ? Ws[layer * DD * DD + k * DD + n]
                           : Wn[layer * DD * DD + (k - DD) * DD + n];
        o[j] = f2bf(w);
    }
    uint4 pk;
    pk.x = (u32)o[0] | ((u32)o[1] << 16);
    pk.y = (u32)o[2] | ((u32)o[3] << 16);
    pk.z = (u32)o[4] | ((u32)o[5] << 16);
    pk.w = (u32)o[6] | ((u32)o[7] << 16);
    *(uint4*)(wpk + (size_t)tid * 8) = pk;
}

// ---------------- mean aggregation: quarter-wave (16 lanes) per edge, uint4 gathers ----------------

__global__ __launch_bounds__(256) void k_agg(const u16* __restrict__ hb,
                                             const int* __restrict__ row_off,
                                             const int* __restrict__ csr,
                                             const float* __restrict__ inv_deg,
                                             u16* __restrict__ agb) {
    int wave = blockIdx.x * 4 + (threadIdx.x >> 6);
    int lane = threadIdx.x & 63;
    if (wave >= NN) return;
    int qt = lane >> 4;     // 0..3: 4 edges in flight per wave
    int l16 = lane & 15;
    int beg = row_off[wave], end = row_off[wave + 1];
    float a[8] = {0.f, 0.f, 0.f, 0.f, 0.f, 0.f, 0.f, 0.f};
#pragma unroll 2
    for (int e = beg + qt; e < end; e += 4) {
        int s = csr[e];
        uint4 u = *(const uint4*)(hb + (size_t)s * DD + l16 * 8);
        a[0] += bf2f((u16)(u.x & 0xffffu)); a[1] += bf2f((u16)(u.x >> 16));
        a[2] += bf2f((u16)(u.y & 0xffffu)); a[3] += bf2f((u16)(u.y >> 16));
        a[4] += bf2f((u16)(u.z & 0xffffu)); a[5] += bf2f((u16)(u.z >> 16));
        a[6] += bf2f((u16)(u.w & 0xffffu)); a[7] += bf2f((u16)(u.w >> 16));
    }
#pragma unroll
    for (int k = 0; k < 8; ++k) {
        a[k] += __shfl_xor(a[k], 16);
        a[k] += __shfl_xor(a[k], 32);
    }
    if (qt == 0) {
        float sc = inv_deg[wave];
        uint4 p;
        p.x = (u32)f2bf(a[0] * sc) | ((u32)f2bf(a[1] * sc) << 16);
        p.y = (u32)f2bf(a[2] * sc) | ((u32)f2bf(a[3] * sc) << 16);
        p.z = (u32)f2bf(a[4] * sc) | ((u32)f2bf(a[5] * sc) << 16);
        p.w = (u32)f2bf(a[6] * sc) | ((u32)f2bf(a[7] * sc) << 16);
        *(uint4*)(agb + (size_t)wave * DD + l16 * 8) = p;
    }
}

// ---------------- MFMA fused SAGEConv layer ----------------
// block = 256 thr = 4 waves, 64 nodes; wave handles 16 rows x 128 cols.
// A = [h_bf16 | agg_bf16] (K=256) staged to LDS; B = packed fragments (k_wpack).
// Epilogue: +bias, +fp32 residual, [ReLU+LN] in C-layout, store fp32 + bf16 shadow.

__global__ __launch_bounds__(256) void k_gemm(const float* __restrict__ h_in,
                                              const u16* __restrict__ hb,
                                              const u16* __restrict__ agb,
                                              const u16* __restrict__ wpk,
                                              const float* __restrict__ bias,
                                              const float* __restrict__ gmm,
                                              const float* __restrict__ bet,
                                              float* __restrict__ h_out,
                                              u16* __restrict__ hb_out,
                                              float* __restrict__ emb_out,
                                              int do_ln) {
    __shared__ u16 A[64 * LDA];   // 33792 B
    int t = threadIdx.x;
    int b0 = blockIdx.x * 64;

    // stage A: h half (cols 0-127) and agg half (cols 128-255), 16B chunks
#pragma unroll
    for (int j = 0; j < 4; ++j) {
        int idx = t + 256 * j;       // 1024 chunks: 64 rows x 16
        int r = idx >> 4;
        int c = idx & 15;            // chunk of 8 u16
        int node = b0 + r;
        uint4 v = make_uint4(0, 0, 0, 0), w = make_uint4(0, 0, 0, 0);
        if (node < NN) {
            v = *(const uint4*)(hb + (size_t)node * DD + c * 8);
            w = *(const uint4*)(agb + (size_t)node * DD + c * 8);
        }
        *(uint4*)&A[r * LDA + c * 8] = v;
        *(uint4*)&A[r * LDA + 128 + c * 8] = w;
    }
    __syncthreads();

    int wv = t >> 6, lane = t & 63;
    int m = lane & 15, q = lane >> 4;

    f32x4 acc[8];
#pragma unroll
    for (int nt = 0; nt < 8; ++nt) acc[nt] = (f32x4)(0.f);

    const u16* Arow = &A[(wv * 16 + m) * LDA + q * 8];
    const short8* wp = (const short8*)wpk;
#pragma unroll
    for (int ks = 0; ks < 8; ++ks) {
        short8 af = *(const short8*)(Arow + ks * 32);
        const short8* bp = wp + (ks * 8) * 64 + lane;
#pragma unroll
        for (int nt = 0; nt < 8; ++nt) {
            short8 bf = bp[nt * 64];
            acc[nt] = __builtin_amdgcn_mfma_f32_16x16x32_bf16(af, bf, acc[nt], 0, 0, 0);
        }
    }

    // per-lane column constants
    float bcol[8], gcol[8], ecol[8];
#pragma unroll
    for (int nt = 0; nt < 8; ++nt) {
        bcol[nt] = bias[nt * 16 + m];
        if (do_ln) { gcol[nt] = gmm[nt * 16 + m]; ecol[nt] = bet[nt * 16 + m]; }
    }

    // epilogue per C-row j: row = q*4+j, node = b0 + wv*16 + q*4 + j
#pragma unroll
    for (int j = 0; j < 4; ++j) {
        int node = b0 + wv * 16 + q * 4 + j;
        bool ok = node < NN;
        const float* hr = h_in + (size_t)node * DD;
        float v[8];
        float s = 0.f, qq = 0.f;
#pragma unroll
        for (int nt = 0; nt < 8; ++nt) {
            float x = acc[nt][j] + bcol[nt];
            if (ok) x += hr[nt * 16 + m];        // fp32 residual
            if (do_ln) {
                x = fmaxf(x, 0.f);
                s += x; qq += x * x;
            }
            v[nt] = x;
        }
        if (do_ln) {
#pragma unroll
            for (int o = 1; o < 16; o <<= 1) {   // reduce across the quad's 16 lanes
                s += __shfl_xor(s, o);
                qq += __shfl_xor(qq, o);
            }
            float mu = s * (1.0f / 128.0f);
            float var = fmaxf(qq * (1.0f / 128.0f) - mu * mu, 0.f);
            float rs = rsqrtf(var + 1e-5f);
#pragma unroll
            for (int nt = 0; nt < 8; ++nt)
                v[nt] = gcol[nt] * (v[nt] - mu) * rs + ecol[nt];
        }
        if (ok) {
            float* orow = h_out + (size_t)node * DD;
#pragma unroll
            for (int nt = 0; nt < 8; ++nt) orow[nt * 16 + m] = v[nt];
            if (hb_out) {
                u16* brow = hb_out + (size_t)node * DD;
#pragma unroll
                for (int nt = 0; nt < 8; ++nt) brow[nt * 16 + m] = f2bf(v[nt]);
            }
            if (emb_out) {
                float* erow = emb_out + (size_t)node * DD;
#pragma unroll
                for (int nt = 0; nt < 8; ++nt) erow[nt * 16 + m] = v[nt];
            }
        }
    }
}

// ---------------- output head: logits = h @ Wout + bout (fp32 vector) ----------------

__device__ __forceinline__ void stage_tile(const float* __restrict__ g, int b0,
                                           float* __restrict__ tile, int t) {
#pragma unroll
    for (int j = 0; j < 8; ++j) {
        int idx = t + 256 * j;
        int r = idx >> 5;
        int c = idx & 31;
        int node = b0 + r;
        float4 f = make_float4(0.f, 0.f, 0.f, 0.f);
        if (node < NN) f = *(const float4*)(g + (size_t)node * DD + c * 4);
        *(float4*)&tile[r * DD + c * 4] = f;
    }
}

__global__ __launch_bounds__(256) void k_logits(const float* __restrict__ h,
                                                const float* __restrict__ Wo,
                                                const float* __restrict__ bo,
                                                float* __restrict__ out) {
    __shared__ float tile[64 * DD];
    int t = threadIdx.x;
    int b0 = blockIdx.x * 64;
    int cg = t & 15;
    int ng = t >> 4;
    stage_tile(h, b0, tile, t);
    __syncthreads();
    float acc[4][4];
#pragma unroll
    for (int i = 0; i < 4; ++i)
#pragma unroll
        for (int j = 0; j < 4; ++j) acc[i][j] = 0.f;
    for (int k = 0; k < DD; k += 4) {
        float4 w0 = *(const float4*)(Wo + (k + 0) * CC + cg * 4);
        float4 w1 = *(const float4*)(Wo + (k + 1) * CC + cg * 4);
        float4 w2 = *(const float4*)(Wo + (k + 2) * CC + cg * 4);
        float4 w3 = *(const float4*)(Wo + (k + 3) * CC + cg * 4);
#pragma unroll
        for (int i = 0; i < 4; ++i) {
            float4 hv = *(const float4*)&tile[(ng * 4 + i) * DD + k];
            acc[i][0] = fmaf(hv.x, w0.x, fmaf(hv.y, w1.x, fmaf(hv.z, w2.x, fmaf(hv.w, w3.x, acc[i][0]))));
            acc[i][1] = fmaf(hv.x, w0.y, fmaf(hv.y, w1.y, fmaf(hv.z, w2.y, fmaf(hv.w, w3.y, acc[i][1]))));
            acc[i][2] = fmaf(hv.x, w0.z, fmaf(hv.y, w1.z, fmaf(hv.z, w2.z, fmaf(hv.w, w3.z, acc[i][2]))));
            acc[i][3] = fmaf(hv.x, w0.w, fmaf(hv.y, w1.w, fmaf(hv.z, w2.w, fmaf(hv.w, w3.w, acc[i][3]))));
        }
    }
    float4 b4 = *(const float4*)(bo + cg * 4);
#pragma unroll
    for (int i = 0; i < 4; ++i) {
        int node = b0 + ng * 4 + i;
        if (node < NN) {
            *(float4*)(out + (size_t)node * CC + cg * 4) =
                make_float4(acc[i][0] + b4.x, acc[i][1] + b4.y,
                            acc[i][2] + b4.z, acc[i][3] + b4.w);
        }
    }
}

// ---------------- launch ----------------

extern "C" void kernel_launch(void* const* d_in, const int* in_sizes, int n_in,
                              void* d_out, int out_size, void* d_ws, size_t ws_size,
                              hipStream_t stream) {
    const float* x  = (const float*)d_in[0];
    const int* src  = (const int*)d_in[1];
    const int* dst  = (const int*)d_in[2];
    const float* Ws = (const float*)d_in[3];
    const float* Wn = (const float*)d_in[4];
    const float* bc = (const float*)d_in[5];
    const float* gm = (const float*)d_in[6];
    const float* bt = (const float*)d_in[7];
    const float* Wo = (const float*)d_in[8];
    const float* bo = (const float*)d_in[9];
    float* out = (float*)d_out;   // fp32: logits [NN*CC] then embedding [NN*DD]

    char* p = (char*)d_ws;
    auto alloc = [&](size_t bytes) { void* r = (void*)p; p += (bytes + 255) & ~(size_t)255; return r; };
    float* h0    = (float*)alloc((size_t)NN * DD * 4);
    float* h1    = (float*)alloc((size_t)NN * DD * 4);
    u16* xb      = (u16*)alloc((size_t)NN * DD * 2);
    u16* hb0     = (u16*)alloc((size_t)NN * DD * 2);
    u16* hb1     = (u16*)alloc((size_t)NN * DD * 2);
    u16* agb     = (u16*)alloc((size_t)NN * DD * 2);
    u16* wpk     = (u16*)alloc((size_t)3 * 4096 * 8 * 2);
    float* invd  = (float*)alloc(NN * 4);
    int* deg     = (int*)alloc(NN * 4);
    int* row_off = (int*)alloc((NN + 1) * 4);
    int* cursor  = (int*)alloc(NN * 4);
    int* bsum    = (int*)alloc(NBLK * 4);
    int* bcnt    = (int*)alloc(NBKT * 4);
    int* csr     = (int*)alloc(EE * 4);
    // bucket pairs (9.6 MB) alias h1: h1 is first written by the layer-1 GEMM,
    // long after k_fill2 has consumed bkt (stream-ordered).
    uint2* bkt   = (uint2*)h1;   // NBKT * BCAP * 8 = 9.6 MB <= 25.6 MB

    hipMemsetAsync(deg, 0, NN * 4, stream);
    hipMemsetAsync(cursor, 0, NN * 4, stream);
    hipMemsetAsync(bcnt, 0, NBKT * 4, stream);

    k_bucket<<<(EE + EPB - 1) / EPB, 1024, 0, stream>>>(src, dst, deg, bcnt, bkt);
    k_bsum<<<NBLK, SCAN_B, 0, stream>>>(deg, bsum);
    k_bscan<<<1, 128, 0, stream>>>(bsum, row_off);
    k_cscan<<<NBLK, SCAN_B, 0, stream>>>(deg, bsum, row_off, invd);
    k_fill2<<<NBKT, 256, 0, stream>>>(bcnt, bkt, row_off, cursor, csr);
    k_x2bf<<<(NN * DD / 4 + 255) / 256, 256, 0, stream>>>(x, xb);
    k_wpack<<<(3 * 4096 + 255) / 256, 256, 0, stream>>>(Ws, Wn, wpk);

    const float* hin = x;
    const u16* hbin = xb;
    float* houts[3] = {h0, h1, h0};
    u16* hbouts[3] = {hb0, hb1, (u16*)nullptr};
    for (int l = 0; l < 3; ++l) {
        k_agg<<<(NN + 3) / 4, 256, 0, stream>>>(hbin, row_off, csr, invd, agb);
        k_gemm<<<(NN + 63) / 64, 256, 0, stream>>>(
            hin, hbin, agb, wpk + (size_t)l * 4096 * 8,
            bc + l * DD,
            (l < 2) ? gm + l * DD : (const float*)nullptr,
            (l < 2) ? bt + l * DD : (const float*)nullptr,
            houts[l], hbouts[l],
            (l == 2) ? out + (size_t)NN * CC : (float*)nullptr,
            (l < 2) ? 1 : 0);
        hin = houts[l];
        hbin = hbouts[l];
    }
    k_logits<<<(NN + 63) / 64, 256, 0, stream>>>(h0, Wo, bo, out);
}

// Round 2
// 311.843 us; speedup vs baseline: 1.2365x; 1.1698x over previous
//
#include <hip/hip_runtime.h>

#define NN 50000
#define EE 800000
#define DD 128
#define CC 64
#define LDA 264    // LDS A row stride in u16: 256 data + 8 pad (2-way bank alias = free)

// bucketed CSR fill
#define BSH 7                                 // 128 dst-nodes per bucket
#define NBKT ((NN + (1 << BSH) - 1) >> BSH)   // 391
#define BCAP 3072                             // mean 2048, sd ~45 -> 22-sigma margin
#define EPB 4096                              // edges per bucket-block (1024 thr x 4)

typedef unsigned short u16;
typedef unsigned int u32;
typedef __attribute__((ext_vector_type(8))) short short8;   // 8 bf16
typedef __attribute__((ext_vector_type(4))) float f32x4;

__device__ __forceinline__ float bf2f(u16 u) {
    union { u32 i; float f; } v; v.i = ((u32)u) << 16; return v.f;
}
__device__ __forceinline__ u16 f2bf(float f) {
    union { float f; u32 i; } v; v.f = f;
    u32 x = v.i;
    u32 r = x + 0x7fffu + ((x >> 16) & 1u);   // round-to-nearest-even
    return (u16)(r >> 16);
}

// ---------------- phase A: bucket edges by dst>>7, NO global per-edge atomics ----------------
// Edge packed to u32: src (16b) | dlocal (7b) << 16. LDS multisplit -> one global
// atomicAdd per (block,bucket) -> contiguous ~10-pair runs inside each bucket.

__global__ __launch_bounds__(1024) void k_bucket(const int* __restrict__ src,
                                                 const int* __restrict__ dst,
                                                 int* __restrict__ bcnt,
                                                 u32* __restrict__ bkt) {
    __shared__ int cnt[NBKT];
    __shared__ int base[NBKT];
    int t = threadIdx.x;
    int e0 = blockIdx.x * EPB;
    for (int i = t; i < NBKT; i += 1024) cnt[i] = 0;
    __syncthreads();
    int bk[4], lp[4];
    u32 pk[4];
#pragma unroll
    for (int j = 0; j < 4; ++j) {
        int e = e0 + t + 1024 * j;
        if (e < EE) {
            int d = dst[e];
            int s = src[e];
            bk[j] = d >> BSH;
            pk[j] = (u32)s | ((u32)(d & 127) << 16);
            lp[j] = atomicAdd(&cnt[bk[j]], 1);
        } else {
            bk[j] = -1;
        }
    }
    __syncthreads();
    for (int i = t; i < NBKT; i += 1024)
        base[i] = atomicAdd(&bcnt[i], cnt[i]);
    __syncthreads();
#pragma unroll
    for (int j = 0; j < 4; ++j) {
        if (bk[j] >= 0)
            bkt[(size_t)bk[j] * BCAP + base[bk[j]] + lp[j]] = pk[j];
    }
}

// ---------------- phase B: one block per bucket. Local deg histogram -> local scan
// -> row_off/inv_deg written directly; LDS-cursor scatter into the bucket's private
// contiguous csr range (~8KB, single-block-owned => full-line writes). ----------------

__global__ __launch_bounds__(512) void k_fill2(const int* __restrict__ bcnt,
                                               const u32* __restrict__ bkt,
                                               int* __restrict__ row_off,
                                               float* __restrict__ inv_deg,
                                               int* __restrict__ csr) {
    __shared__ int cnt[128];
    __shared__ int off[128];
    __shared__ int wtot;
    int b = blockIdx.x;
    int t = threadIdx.x;
    int lane = t & 63;
    int n = bcnt[b];

    // exclusive prefix of bcnt[0..b) -- redundant per-wave reduce, L2-hot
    int part = 0;
    for (int i = lane; i < b; i += 64) part += bcnt[i];
#pragma unroll
    for (int o = 1; o < 64; o <<= 1) part += __shfl_xor(part, o);
    int gbase = part;   // same value in every wave

    if (t < 128) cnt[t] = 0;
    __syncthreads();

    const u32* bp = bkt + (size_t)b * BCAP;
    int dl[6], sv[6], lp[6];
#pragma unroll
    for (int j = 0; j < 6; ++j) {           // BCAP/512 = 6
        int i = t + 512 * j;
        if (i < n) {
            u32 pk = bp[i];
            dl[j] = (int)(pk >> 16) & 127;
            sv[j] = (int)(pk & 0xffffu);
            lp[j] = atomicAdd(&cnt[dl[j]], 1);
        } else {
            dl[j] = -1;
        }
    }
    __syncthreads();

    // scan cnt[128] -> off (exclusive), emit row_off / inv_deg
    int x = 0, v = 0;
    if (t < 128) {
        v = cnt[t];
        x = v;
#pragma unroll
        for (int o = 1; o < 64; o <<= 1) {
            int y = __shfl_up(x, o, 64);
            if (lane >= o) x += y;
        }
        if (t == 63) wtot = x;
    }
    __syncthreads();
    if (t < 128) {
        int excl = x - v + ((t >= 64) ? wtot : 0);
        off[t] = excl;
        int node = (b << BSH) + t;
        if (node < NN) {
            row_off[node] = gbase + excl;
            inv_deg[node] = 1.0f / fmaxf((float)v, 1.0f);
        } else if (node == NN) {
            row_off[NN] = gbase + excl;   // == EE
        }
    }
    __syncthreads();

    int* cp = csr + gbase;
#pragma unroll
    for (int j = 0; j < 6; ++j) {
        if (dl[j] >= 0) cp[off[dl[j]] + lp[j]] = sv[j];
    }
}

// ---------------- x -> bf16 shadow ----------------

__global__ __launch_bounds__(256) void k_x2bf(const float* __restrict__ x,
                                              u16* __restrict__ xb) {
    int i = (blockIdx.x * 256 + threadIdx.x) * 4;
    if (i < NN * DD) {
        float4 v = *(const float4*)(x + i);
        uint2 p;
        p.x = (u32)f2bf(v.x) | ((u32)f2bf(v.y) << 16);
        p.y = (u32)f2bf(v.z) | ((u32)f2bf(v.w) << 16);
        *(uint2*)(xb + i) = p;
    }
}

// ---------------- weight pack: [Ws;Wn] (256x128) -> MFMA B-fragment order, bf16 ----------------
// frag (ks,nt,lane) holds B[ks*32 + (lane>>4)*8 + j][nt*16 + (lane&15)], j=0..7 contiguous.

__global__ __launch_bounds__(256) void k_wpack(const float* __restrict__ Ws,
                                               const float* __restrict__ Wn,
                                               u16* __restrict__ wpk) {
    int tid = blockIdx.x * 256 + threadIdx.x;   // 3 layers * 4096 frags
    if (tid >= 3 * 4096) return;
    int layer = tid >> 12;
    int rem = tid & 4095;
    int ks = rem >> 9;
    int nt = (rem >> 6) & 7;
    int lane = rem & 63;
    int n = nt * 16 + (lane & 15);
    int kb = ks * 32 + (lane >> 4) * 8;
    u16 o[8];
#pragma unroll
    for (int j = 0; j < 8; ++j) {
        int k = kb + j;
        float w = (k < DD) ? Ws[layer * DD * DD + k * DD + n]
                           : Wn[layer * DD * DD + (k - DD) * DD + n];
        o[j] = f2bf(w);
    }
    uint4 pk;
    pk.x = (u32)o[0] | ((u32)o[1] << 16);
    pk.y = (u32)o[2] | ((u32)o[3] << 16);
    pk.z = (u32)o[4] | ((u32)o[5] << 16);
    pk.w = (u32)o[6] | ((u32)o[7] << 16);
    *(uint4*)(wpk + (size_t)tid * 8) = pk;
}

// ---------------- mean aggregation: quarter-wave (16 lanes) per edge, uint4 gathers ----------------

__global__ __launch_bounds__(256) void k_agg(const u16* __restrict__ hb,
                                             const int* __restrict__ row_off,
                                             const int* __restrict__ csr,
                                             const float* __restrict__ inv_deg,
                                             u16* __restrict__ agb) {
    int wave = blockIdx.x * 4 + (threadIdx.x >> 6);
    int lane = threadIdx.x & 63;
    if (wave >= NN) return;
    int qt = lane >> 4;     // 0..3: 4 edges in flight per wave
    int l16 = lane & 15;
    int beg = row_off[wave], end = row_off[wave + 1];
    float a[8] = {0.f, 0.f, 0.f, 0.f, 0.f, 0.f, 0.f, 0.f};
#pragma unroll 2
    for (int e = beg + qt; e < end; e += 4) {
        int s = csr[e];
        uint4 u = *(const uint4*)(hb + (size_t)s * DD + l16 * 8);
        a[0] += bf2f((u16)(u.x & 0xffffu)); a[1] += bf2f((u16)(u.x >> 16));
        a[2] += bf2f((u16)(u.y & 0xffffu)); a[3] += bf2f((u16)(u.y >> 16));
        a[4] += bf2f((u16)(u.z & 0xffffu)); a[5] += bf2f((u16)(u.z >> 16));
        a[6] += bf2f((u16)(u.w & 0xffffu)); a[7] += bf2f((u16)(u.w >> 16));
    }
#pragma unroll
    for (int k = 0; k < 8; ++k) {
        a[k] += __shfl_xor(a[k], 16);
        a[k] += __shfl_xor(a[k], 32);
    }
    if (qt == 0) {
        float sc = inv_deg[wave];
        uint4 p;
        p.x = (u32)f2bf(a[0] * sc) | ((u32)f2bf(a[1] * sc) << 16);
        p.y = (u32)f2bf(a[2] * sc) | ((u32)f2bf(a[3] * sc) << 16);
        p.z = (u32)f2bf(a[4] * sc) | ((u32)f2bf(a[5] * sc) << 16);
        p.w = (u32)f2bf(a[6] * sc) | ((u32)f2bf(a[7] * sc) << 16);
        *(uint4*)(agb + (size_t)wave * DD + l16 * 8) = p;
    }
}

// ---------------- MFMA fused SAGEConv layer ----------------
// block = 256 thr = 4 waves, 64 nodes; wave handles 16 rows x 128 cols.
// A = [h_bf16 | agg_bf16] (K=256) staged to LDS; B = packed fragments (k_wpack).
// Epilogue: +bias, +fp32 residual, [ReLU+LN] in C-layout, store fp32 + bf16 shadow.

__global__ __launch_bounds__(256) void k_gemm(const float* __restrict__ h_in,
                                              const u16* __restrict__ hb,
                                              const u16* __restrict__ agb,
                                              const u16* __restrict__ wpk,
                                              const float* __restrict__ bias,
                                              const float* __restrict__ gmm,
                                              const float* __restrict__ bet,
                                              float* __restrict__ h_out,
                                              u16* __restrict__ hb_out,
                                              float* __restrict__ emb_out,
                                              int do_ln) {
    __shared__ u16 A[64 * LDA];   // 33792 B
    int t = threadIdx.x;
    int b0 = blockIdx.x * 64;

    // stage A: h half (cols 0-127) and agg half (cols 128-255), 16B chunks
#pragma unroll
    for (int j = 0; j < 4; ++j) {
        int idx = t + 256 * j;       // 1024 chunks: 64 rows x 16
        int r = idx >> 4;
        int c = idx & 15;            // chunk of 8 u16
        int node = b0 + r;
        uint4 v = make_uint4(0, 0, 0, 0), w = make_uint4(0, 0, 0, 0);
        if (node < NN) {
            v = *(const uint4*)(hb + (size_t)node * DD + c * 8);
            w = *(const uint4*)(agb + (size_t)node * DD + c * 8);
        }
        *(uint4*)&A[r * LDA + c * 8] = v;
        *(uint4*)&A[r * LDA + 128 + c * 8] = w;
    }
    __syncthreads();

    int wv = t >> 6, lane = t & 63;
    int m = lane & 15, q = lane >> 4;

    f32x4 acc[8];
#pragma unroll
    for (int nt = 0; nt < 8; ++nt) acc[nt] = (f32x4)(0.f);

    const u16* Arow = &A[(wv * 16 + m) * LDA + q * 8];
    const short8* wp = (const short8*)wpk;
#pragma unroll
    for (int ks = 0; ks < 8; ++ks) {
        short8 af = *(const short8*)(Arow + ks * 32);
        const short8* bp = wp + (ks * 8) * 64 + lane;
#pragma unroll
        for (int nt = 0; nt < 8; ++nt) {
            short8 bf = bp[nt * 64];
            acc[nt] = __builtin_amdgcn_mfma_f32_16x16x32_bf16(af, bf, acc[nt], 0, 0, 0);
        }
    }

    // per-lane column constants
    float bcol[8], gcol[8], ecol[8];
#pragma unroll
    for (int nt = 0; nt < 8; ++nt) {
        bcol[nt] = bias[nt * 16 + m];
        if (do_ln) { gcol[nt] = gmm[nt * 16 + m]; ecol[nt] = bet[nt * 16 + m]; }
    }

    // epilogue per C-row j: row = q*4+j, node = b0 + wv*16 + q*4 + j
#pragma unroll
    for (int j = 0; j < 4; ++j) {
        int node = b0 + wv * 16 + q * 4 + j;
        bool ok = node < NN;
        const float* hr = h_in + (size_t)node * DD;
        float v[8];
        float s = 0.f, qq = 0.f;
#pragma unroll
        for (int nt = 0; nt < 8; ++nt) {
            float x = acc[nt][j] + bcol[nt];
            if (ok) x += hr[nt * 16 + m];        // fp32 residual
            if (do_ln) {
                x = fmaxf(x, 0.f);
                s += x; qq += x * x;
            }
            v[nt] = x;
        }
        if (do_ln) {
#pragma unroll
            for (int o = 1; o < 16; o <<= 1) {   // reduce across the quad's 16 lanes
                s += __shfl_xor(s, o);
                qq += __shfl_xor(qq, o);
            }
            float mu = s * (1.0f / 128.0f);
            float var = fmaxf(qq * (1.0f / 128.0f) - mu * mu, 0.f);
            float rs = rsqrtf(var + 1e-5f);
#pragma unroll
            for (int nt = 0; nt < 8; ++nt)
                v[nt] = gcol[nt] * (v[nt] - mu) * rs + ecol[nt];
        }
        if (ok) {
            float* orow = h_out + (size_t)node * DD;
#pragma unroll
            for (int nt = 0; nt < 8; ++nt) orow[nt * 16 + m] = v[nt];
            if (hb_out) {
                u16* brow = hb_out + (size_t)node * DD;
#pragma unroll
                for (int nt = 0; nt < 8; ++nt) brow[nt * 16 + m] = f2bf(v[nt]);
            }
            if (emb_out) {
                float* erow = emb_out + (size_t)node * DD;
#pragma unroll
                for (int nt = 0; nt < 8; ++nt) erow[nt * 16 + m] = v[nt];
            }
        }
    }
}

// ---------------- output head: logits = h @ Wout + bout (fp32 vector) ----------------

__device__ __forceinline__ void stage_tile(const float* __restrict__ g, int b0,
                                           float* __restrict__ tile, int t) {
#pragma unroll
    for (int j = 0; j < 8; ++j) {
        int idx = t + 256 * j;
        int r = idx >> 5;
        int c = idx & 31;
        int node = b0 + r;
        float4 f = make_float4(0.f, 0.f, 0.f, 0.f);
        if (node < NN) f = *(const float4*)(g + (size_t)node * DD + c * 4);
        *(float4*)&tile[r * DD + c * 4] = f;
    }
}

__global__ __launch_bounds__(256) void k_logits(const float* __restrict__ h,
                                                const float* __restrict__ Wo,
                                                const float* __restrict__ bo,
                                                float* __restrict__ out) {
    __shared__ float tile[64 * DD];
    int t = threadIdx.x;
    int b0 = blockIdx.x * 64;
    int cg = t & 15;
    int ng = t >> 4;
    stage_tile(h, b0, tile, t);
    __syncthreads();
    float acc[4][4];
#pragma unroll
    for (int i = 0; i < 4; ++i)
#pragma unroll
        for (int j = 0; j < 4; ++j) acc[i][j] = 0.f;
    for (int k = 0; k < DD; k += 4) {
        float4 w0 = *(const float4*)(Wo + (k + 0) * CC + cg * 4);
        float4 w1 = *(const float4*)(Wo + (k + 1) * CC + cg * 4);
        float4 w2 = *(const float4*)(Wo + (k + 2) * CC + cg * 4);
        float4 w3 = *(const float4*)(Wo + (k + 3) * CC + cg * 4);
#pragma unroll
        for (int i = 0; i < 4; ++i) {
            float4 hv = *(const float4*)&tile[(ng * 4 + i) * DD + k];
            acc[i][0] = fmaf(hv.x, w0.x, fmaf(hv.y, w1.x, fmaf(hv.z, w2.x, fmaf(hv.w, w3.x, acc[i][0]))));
            acc[i][1] = fmaf(hv.x, w0.y, fmaf(hv.y, w1.y, fmaf(hv.z, w2.y, fmaf(hv.w, w3.y, acc[i][1]))));
            acc[i][2] = fmaf(hv.x, w0.z, fmaf(hv.y, w1.z, fmaf(hv.z, w2.z, fmaf(hv.w, w3.z, acc[i][2]))));
            acc[i][3] = fmaf(hv.x, w0.w, fmaf(hv.y, w1.w, fmaf(hv.z, w2.w, fmaf(hv.w, w3.w, acc[i][3]))));
        }
    }
    float4 b4 = *(const float4*)(bo + cg * 4);
#pragma unroll
    for (int i = 0; i < 4; ++i) {
        int node = b0 + ng * 4 + i;
        if (node < NN) {
            *(float4*)(out + (size_t)node * CC + cg * 4) =
                make_float4(acc[i][0] + b4.x, acc[i][1] + b4.y,
                            acc[i][2] + b4.z, acc[i][3] + b4.w);
        }
    }
}

// ---------------- launch ----------------

extern "C" void kernel_launch(void* const* d_in, const int* in_sizes, int n_in,
                              void* d_out, int out_size, void* d_ws, size_t ws_size,
                              hipStream_t stream) {
    const float* x  = (const float*)d_in[0];
    const int* src  = (const int*)d_in[1];
    const int* dst  = (const int*)d_in[2];
    const float* Ws = (const float*)d_in[3];
    const float* Wn = (const float*)d_in[4];
    const float* bc = (const float*)d_in[5];
    const float* gm = (const float*)d_in[6];
    const float* bt = (const float*)d_in[7];
    const float* Wo = (const float*)d_in[8];
    const float* bo = (const float*)d_in[9];
    float* out = (float*)d_out;   // fp32: logits [NN*CC] then embedding [NN*DD]

    char* p = (char*)d_ws;
    auto alloc = [&](size_t bytes) { void* r = (void*)p; p += (bytes + 255) & ~(size_t)255; return r; };
    float* h0    = (float*)alloc((size_t)NN * DD * 4);
    float* h1    = (float*)alloc((size_t)NN * DD * 4);
    u16* xb      = (u16*)alloc((size_t)NN * DD * 2);
    u16* hb0     = (u16*)alloc((size_t)NN * DD * 2);
    u16* hb1     = (u16*)alloc((size_t)NN * DD * 2);
    u16* agb     = (u16*)alloc((size_t)NN * DD * 2);
    u16* wpk     = (u16*)alloc((size_t)3 * 4096 * 8 * 2);
    float* invd  = (float*)alloc(NN * 4);
    int* row_off = (int*)alloc((NN + 1) * 4);
    int* bcnt    = (int*)alloc(NBKT * 4);
    int* csr     = (int*)alloc(EE * 4);
    // bucket pairs (4.8 MB) alias h1: h1 is first written by the layer-1 GEMM,
    // long after k_fill2 has consumed bkt (stream-ordered).
    u32* bkt     = (u32*)h1;   // NBKT * BCAP * 4 = 4.8 MB <= 25.6 MB

    hipMemsetAsync(bcnt, 0, NBKT * 4, stream);

    k_bucket<<<(EE + EPB - 1) / EPB, 1024, 0, stream>>>(src, dst, bcnt, bkt);
    k_fill2<<<NBKT, 512, 0, stream>>>(bcnt, bkt, row_off, invd, csr);
    k_x2bf<<<(NN * DD / 4 + 255) / 256, 256, 0, stream>>>(x, xb);
    k_wpack<<<(3 * 4096 + 255) / 256, 256, 0, stream>>>(Ws, Wn, wpk);

    const float* hin = x;
    const u16* hbin = xb;
    float* houts[3] = {h0, h1, h0};
    u16* hbouts[3] = {hb0, hb1, (u16*)nullptr};
    for (int l = 0; l < 3; ++l) {
        k_agg<<<(NN + 3) / 4, 256, 0, stream>>>(hbin, row_off, csr, invd, agb);
        k_gemm<<<(NN + 63) / 64, 256, 0, stream>>>(
            hin, hbin, agb, wpk + (size_t)l * 4096 * 8,
            bc + l * DD,
            (l < 2) ? gm + l * DD : (const float*)nullptr,
            (l < 2) ? bt + l * DD : (const float*)nullptr,
            houts[l], hbouts[l],
            (l == 2) ? out + (size_t)NN * CC : (float*)nullptr,
            (l < 2) ? 1 : 0);
        hin = houts[l];
        hbin = hbouts[l];
    }
    k_logits<<<(NN + 63) / 64, 256, 0, stream>>>(h0, Wo, bo, out);
}

// Round 3
// 306.945 us; speedup vs baseline: 1.2563x; 1.0160x over previous
//
#include <hip/hip_runtime.h>

#define NN 50000
#define EE 800000
#define DD 128
#define CC 64
#define LDA 264    // LDS A row stride in u16: 256 data + 8 pad (2-way bank alias = free)

// bucketed CSR fill
#define BSH 7                                 // 128 dst-nodes per bucket
#define NBKT ((NN + (1 << BSH) - 1) >> BSH)   // 391
#define BCAP 3072                             // mean 2048, sd ~45 -> 22-sigma margin
#define EPB 4096                              // edges per bucket-block (1024 thr x 4)

typedef unsigned short u16;
typedef unsigned int u32;
typedef __attribute__((ext_vector_type(8))) short short8;   // 8 bf16
typedef __attribute__((ext_vector_type(4))) float f32x4;

__device__ __forceinline__ float bf2f(u16 u) {
    union { u32 i; float f; } v; v.i = ((u32)u) << 16; return v.f;
}
__device__ __forceinline__ u16 f2bf(float f) {
    union { float f; u32 i; } v; v.f = f;
    u32 x = v.i;
    u32 r = x + 0x7fffu + ((x >> 16) & 1u);   // round-to-nearest-even
    return (u16)(r >> 16);
}

// ---------------- phase A: bucket edges by dst>>7, NO global per-edge atomics ----------------

__global__ __launch_bounds__(1024) void k_bucket(const int* __restrict__ src,
                                                 const int* __restrict__ dst,
                                                 int* __restrict__ bcnt,
                                                 u32* __restrict__ bkt) {
    __shared__ int cnt[NBKT];
    __shared__ int base[NBKT];
    int t = threadIdx.x;
    int e0 = blockIdx.x * EPB;
    for (int i = t; i < NBKT; i += 1024) cnt[i] = 0;
    __syncthreads();
    int bk[4], lp[4];
    u32 pk[4];
#pragma unroll
    for (int j = 0; j < 4; ++j) {
        int e = e0 + t + 1024 * j;
        if (e < EE) {
            int d = dst[e];
            int s = src[e];
            bk[j] = d >> BSH;
            pk[j] = (u32)s | ((u32)(d & 127) << 16);
            lp[j] = atomicAdd(&cnt[bk[j]], 1);
        } else {
            bk[j] = -1;
        }
    }
    __syncthreads();
    for (int i = t; i < NBKT; i += 1024)
        base[i] = atomicAdd(&bcnt[i], cnt[i]);
    __syncthreads();
#pragma unroll
    for (int j = 0; j < 4; ++j) {
        if (bk[j] >= 0)
            bkt[(size_t)bk[j] * BCAP + base[bk[j]] + lp[j]] = pk[j];
    }
}

// ---------------- phase B: one block per bucket: local histogram/scan -> row_off,
// inv_deg, csr (all contiguous single-block-owned writes) ----------------

__global__ __launch_bounds__(512) void k_fill2(const int* __restrict__ bcnt,
                                               const u32* __restrict__ bkt,
                                               int* __restrict__ row_off,
                                               float* __restrict__ inv_deg,
                                               int* __restrict__ csr) {
    __shared__ int cnt[128];
    __shared__ int off[128];
    __shared__ int wtot;
    int b = blockIdx.x;
    int t = threadIdx.x;
    int lane = t & 63;
    int n = bcnt[b];

    // exclusive prefix of bcnt[0..b) -- redundant per-wave reduce, L2-hot
    int part = 0;
    for (int i = lane; i < b; i += 64) part += bcnt[i];
#pragma unroll
    for (int o = 1; o < 64; o <<= 1) part += __shfl_xor(part, o);
    int gbase = part;   // same value in every wave

    if (t < 128) cnt[t] = 0;
    __syncthreads();

    const u32* bp = bkt + (size_t)b * BCAP;
    int dl[6], sv[6], lp[6];
#pragma unroll
    for (int j = 0; j < 6; ++j) {           // BCAP/512 = 6
        int i = t + 512 * j;
        if (i < n) {
            u32 pk = bp[i];
            dl[j] = (int)(pk >> 16) & 127;
            sv[j] = (int)(pk & 0xffffu);
            lp[j] = atomicAdd(&cnt[dl[j]], 1);
        } else {
            dl[j] = -1;
        }
    }
    __syncthreads();

    int x = 0, v = 0;
    if (t < 128) {
        v = cnt[t];
        x = v;
#pragma unroll
        for (int o = 1; o < 64; o <<= 1) {
            int y = __shfl_up(x, o, 64);
            if (lane >= o) x += y;
        }
        if (t == 63) wtot = x;
    }
    __syncthreads();
    if (t < 128) {
        int excl = x - v + ((t >= 64) ? wtot : 0);
        off[t] = excl;
        int node = (b << BSH) + t;
        if (node < NN) {
            row_off[node] = gbase + excl;
            inv_deg[node] = 1.0f / fmaxf((float)v, 1.0f);
        } else if (node == NN) {
            row_off[NN] = gbase + excl;   // == EE
        }
    }
    __syncthreads();

    int* cp = csr + gbase;
#pragma unroll
    for (int j = 0; j < 6; ++j) {
        if (dl[j] >= 0) cp[off[dl[j]] + lp[j]] = sv[j];
    }
}

// ---------------- x -> bf16 shadow ----------------

__global__ __launch_bounds__(256) void k_x2bf(const float* __restrict__ x,
                                              u16* __restrict__ xb) {
    int i = (blockIdx.x * 256 + threadIdx.x) * 4;
    if (i < NN * DD) {
        float4 v = *(const float4*)(x + i);
        uint2 p;
        p.x = (u32)f2bf(v.x) | ((u32)f2bf(v.y) << 16);
        p.y = (u32)f2bf(v.z) | ((u32)f2bf(v.w) << 16);
        *(uint2*)(xb + i) = p;
    }
}

// ---------------- weight pack: [Ws;Wn] (256x128) -> MFMA B-fragment order, bf16 ----------------

__global__ __launch_bounds__(256) void k_wpack(const float* __restrict__ Ws,
                                               const float* __restrict__ Wn,
                                               u16* __restrict__ wpk) {
    int tid = blockIdx.x * 256 + threadIdx.x;   // 3 layers * 4096 frags
    if (tid >= 3 * 4096) return;
    int layer = tid >> 12;
    int rem = tid & 4095;
    int ks = rem >> 9;
    int nt = (rem >> 6) & 7;
    int lane = rem & 63;
    int n = nt * 16 + (lane & 15);
    int kb = ks * 32 + (lane >> 4) * 8;
    u16 o[8];
#pragma unroll
    for (int j = 0; j < 8; ++j) {
        int k = kb + j;
        float w = (k < DD) ? Ws[layer * DD * DD + k * DD + n]
                           : Wn[layer * DD * DD + (k - DD) * DD + n];
        o[j] = f2bf(w);
    }
    uint4 pk;
    pk.x = (u32)o[0] | ((u32)o[1] << 16);
    pk.y = (u32)o[2] | ((u32)o[3] << 16);
    pk.z = (u32)o[4] | ((u32)o[5] << 16);
    pk.w = (u32)o[6] | ((u32)o[7] << 16);
    *(uint4*)(wpk + (size_t)tid * 8) = pk;
}

// ---------------- fused SAGEConv layer: gather-mean + MFMA GEMM + epilogue ----------------
// block = 256 thr = 4 waves, 64 nodes. A = [h_bf16 | agg_bf16] (K=256) in LDS.
// h-half staged from hb; agg-half computed IN-KERNEL: one quarter-wave (16 lanes
// x 16B = full 256B row) per node, 4 nodes per quad, edge loop unrolled x4 for MLP.

__device__ __forceinline__ void acc8(float* a, uint4 u) {
    a[0] += bf2f((u16)(u.x & 0xffffu)); a[1] += bf2f((u16)(u.x >> 16));
    a[2] += bf2f((u16)(u.y & 0xffffu)); a[3] += bf2f((u16)(u.y >> 16));
    a[4] += bf2f((u16)(u.z & 0xffffu)); a[5] += bf2f((u16)(u.z >> 16));
    a[6] += bf2f((u16)(u.w & 0xffffu)); a[7] += bf2f((u16)(u.w >> 16));
}

__global__ __launch_bounds__(256) void k_layer(const float* __restrict__ h_in,
                                               const u16* __restrict__ hb,
                                               const int* __restrict__ row_off,
                                               const int* __restrict__ csr,
                                               const float* __restrict__ inv_deg,
                                               const u16* __restrict__ wpk,
                                               const float* __restrict__ bias,
                                               const float* __restrict__ gmm,
                                               const float* __restrict__ bet,
                                               float* __restrict__ h_out,
                                               u16* __restrict__ hb_out,
                                               int do_ln) {
    __shared__ u16 A[64 * LDA];   // 33792 B
    int t = threadIdx.x;
    int b0 = blockIdx.x * 64;

    // stage h half (cols 0-127): 1024 chunks of 16B
#pragma unroll
    for (int j = 0; j < 4; ++j) {
        int idx = t + 256 * j;
        int r = idx >> 4;
        int c = idx & 15;
        int node = b0 + r;
        uint4 v = make_uint4(0, 0, 0, 0);
        if (node < NN) v = *(const uint4*)(hb + (size_t)node * DD + c * 8);
        *(uint4*)&A[r * LDA + c * 8] = v;
    }

    // gather-mean agg half (cols 128-255): quad -> rows quad*4 .. quad*4+3
    int quad = t >> 4;          // 0..15
    int l16 = t & 15;
#pragma unroll
    for (int nn = 0; nn < 4; ++nn) {
        int r = quad * 4 + nn;
        int node = b0 + r;
        uint4 p = make_uint4(0, 0, 0, 0);
        if (node < NN) {
            float a[8] = {0.f, 0.f, 0.f, 0.f, 0.f, 0.f, 0.f, 0.f};
            int beg = row_off[node], end = row_off[node + 1];
            int e = beg;
            for (; e + 4 <= end; e += 4) {
                int s0 = csr[e + 0], s1 = csr[e + 1];
                int s2 = csr[e + 2], s3 = csr[e + 3];
                uint4 u0 = *(const uint4*)(hb + (size_t)s0 * DD + l16 * 8);
                uint4 u1 = *(const uint4*)(hb + (size_t)s1 * DD + l16 * 8);
                uint4 u2 = *(const uint4*)(hb + (size_t)s2 * DD + l16 * 8);
                uint4 u3 = *(const uint4*)(hb + (size_t)s3 * DD + l16 * 8);
                acc8(a, u0); acc8(a, u1); acc8(a, u2); acc8(a, u3);
            }
            for (; e < end; ++e) {
                int s0 = csr[e];
                uint4 u0 = *(const uint4*)(hb + (size_t)s0 * DD + l16 * 8);
                acc8(a, u0);
            }
            float sc = inv_deg[node];
            p.x = (u32)f2bf(a[0] * sc) | ((u32)f2bf(a[1] * sc) << 16);
            p.y = (u32)f2bf(a[2] * sc) | ((u32)f2bf(a[3] * sc) << 16);
            p.z = (u32)f2bf(a[4] * sc) | ((u32)f2bf(a[5] * sc) << 16);
            p.w = (u32)f2bf(a[6] * sc) | ((u32)f2bf(a[7] * sc) << 16);
        }
        *(uint4*)&A[r * LDA + 128 + l16 * 8] = p;
    }
    __syncthreads();

    int wv = t >> 6, lane = t & 63;
    int m = lane & 15, q = lane >> 4;

    f32x4 acc[8];
#pragma unroll
    for (int nt = 0; nt < 8; ++nt) acc[nt] = (f32x4)(0.f);

    const u16* Arow = &A[(wv * 16 + m) * LDA + q * 8];
    const short8* wp = (const short8*)wpk;
#pragma unroll
    for (int ks = 0; ks < 8; ++ks) {
        short8 af = *(const short8*)(Arow + ks * 32);
        const short8* bp = wp + (ks * 8) * 64 + lane;
#pragma unroll
        for (int nt = 0; nt < 8; ++nt) {
            short8 bf = bp[nt * 64];
            acc[nt] = __builtin_amdgcn_mfma_f32_16x16x32_bf16(af, bf, acc[nt], 0, 0, 0);
        }
    }

    // per-lane column constants
    float bcol[8], gcol[8], ecol[8];
#pragma unroll
    for (int nt = 0; nt < 8; ++nt) {
        bcol[nt] = bias[nt * 16 + m];
        if (do_ln) { gcol[nt] = gmm[nt * 16 + m]; ecol[nt] = bet[nt * 16 + m]; }
    }

    // epilogue per C-row j: node = b0 + wv*16 + q*4 + j
#pragma unroll
    for (int j = 0; j < 4; ++j) {
        int node = b0 + wv * 16 + q * 4 + j;
        bool ok = node < NN;
        const float* hr = h_in + (size_t)node * DD;
        float v[8];
        float s = 0.f, qq = 0.f;
#pragma unroll
        for (int nt = 0; nt < 8; ++nt) {
            float x = acc[nt][j] + bcol[nt];
            if (ok) x += hr[nt * 16 + m];        // fp32 residual
            if (do_ln) {
                x = fmaxf(x, 0.f);
                s += x; qq += x * x;
            }
            v[nt] = x;
        }
        if (do_ln) {
#pragma unroll
            for (int o = 1; o < 16; o <<= 1) {
                s += __shfl_xor(s, o);
                qq += __shfl_xor(qq, o);
            }
            float mu = s * (1.0f / 128.0f);
            float var = fmaxf(qq * (1.0f / 128.0f) - mu * mu, 0.f);
            float rs = rsqrtf(var + 1e-5f);
#pragma unroll
            for (int nt = 0; nt < 8; ++nt)
                v[nt] = gcol[nt] * (v[nt] - mu) * rs + ecol[nt];
        }
        if (ok) {
            float* orow = h_out + (size_t)node * DD;
#pragma unroll
            for (int nt = 0; nt < 8; ++nt) orow[nt * 16 + m] = v[nt];
            if (hb_out) {
                u16* brow = hb_out + (size_t)node * DD;
#pragma unroll
                for (int nt = 0; nt < 8; ++nt) brow[nt * 16 + m] = f2bf(v[nt]);
            }
        }
    }
}

// ---------------- output head: logits = h @ Wout + bout (fp32 vector) ----------------

__device__ __forceinline__ void stage_tile(const float* __restrict__ g, int b0,
                                           float* __restrict__ tile, int t) {
#pragma unroll
    for (int j = 0; j < 8; ++j) {
        int idx = t + 256 * j;
        int r = idx >> 5;
        int c = idx & 31;
        int node = b0 + r;
        float4 f = make_float4(0.f, 0.f, 0.f, 0.f);
        if (node < NN) f = *(const float4*)(g + (size_t)node * DD + c * 4);
        *(float4*)&tile[r * DD + c * 4] = f;
    }
}

__global__ __launch_bounds__(256) void k_logits(const float* __restrict__ h,
                                                const float* __restrict__ Wo,
                                                const float* __restrict__ bo,
                                                float* __restrict__ out) {
    __shared__ float tile[64 * DD];
    int t = threadIdx.x;
    int b0 = blockIdx.x * 64;
    int cg = t & 15;
    int ng = t >> 4;
    stage_tile(h, b0, tile, t);
    __syncthreads();
    float acc[4][4];
#pragma unroll
    for (int i = 0; i < 4; ++i)
#pragma unroll
        for (int j = 0; j < 4; ++j) acc[i][j] = 0.f;
    for (int k = 0; k < DD; k += 4) {
        float4 w0 = *(const float4*)(Wo + (k + 0) * CC + cg * 4);
        float4 w1 = *(const float4*)(Wo + (k + 1) * CC + cg * 4);
        float4 w2 = *(const float4*)(Wo + (k + 2) * CC + cg * 4);
        float4 w3 = *(const float4*)(Wo + (k + 3) * CC + cg * 4);
#pragma unroll
        for (int i = 0; i < 4; ++i) {
            float4 hv = *(const float4*)&tile[(ng * 4 + i) * DD + k];
            acc[i][0] = fmaf(hv.x, w0.x, fmaf(hv.y, w1.x, fmaf(hv.z, w2.x, fmaf(hv.w, w3.x, acc[i][0]))));
            acc[i][1] = fmaf(hv.x, w0.y, fmaf(hv.y, w1.y, fmaf(hv.z, w2.y, fmaf(hv.w, w3.y, acc[i][1]))));
            acc[i][2] = fmaf(hv.x, w0.z, fmaf(hv.y, w1.z, fmaf(hv.z, w2.z, fmaf(hv.w, w3.z, acc[i][2]))));
            acc[i][3] = fmaf(hv.x, w0.w, fmaf(hv.y, w1.w, fmaf(hv.z, w2.w, fmaf(hv.w, w3.w, acc[i][3]))));
        }
    }
    float4 b4 = *(const float4*)(bo + cg * 4);
#pragma unroll
    for (int i = 0; i < 4; ++i) {
        int node = b0 + ng * 4 + i;
        if (node < NN) {
            *(float4*)(out + (size_t)node * CC + cg * 4) =
                make_float4(acc[i][0] + b4.x, acc[i][1] + b4.y,
                            acc[i][2] + b4.z, acc[i][3] + b4.w);
        }
    }
}

// ---------------- launch ----------------

extern "C" void kernel_launch(void* const* d_in, const int* in_sizes, int n_in,
                              void* d_out, int out_size, void* d_ws, size_t ws_size,
                              hipStream_t stream) {
    const float* x  = (const float*)d_in[0];
    const int* src  = (const int*)d_in[1];
    const int* dst  = (const int*)d_in[2];
    const float* Ws = (const float*)d_in[3];
    const float* Wn = (const float*)d_in[4];
    const float* bc = (const float*)d_in[5];
    const float* gm = (const float*)d_in[6];
    const float* bt = (const float*)d_in[7];
    const float* Wo = (const float*)d_in[8];
    const float* bo = (const float*)d_in[9];
    float* out = (float*)d_out;   // fp32: logits [NN*CC] then embedding [NN*DD]
    float* emb = out + (size_t)NN * CC;

    char* p = (char*)d_ws;
    auto alloc = [&](size_t bytes) { void* r = (void*)p; p += (bytes + 255) & ~(size_t)255; return r; };
    float* h0    = (float*)alloc((size_t)NN * DD * 4);
    float* h1    = (float*)alloc((size_t)NN * DD * 4);
    u16* xb      = (u16*)alloc((size_t)NN * DD * 2);
    u16* hb0     = (u16*)alloc((size_t)NN * DD * 2);
    u16* hb1     = (u16*)alloc((size_t)NN * DD * 2);
    u16* wpk     = (u16*)alloc((size_t)3 * 4096 * 8 * 2);
    float* invd  = (float*)alloc(NN * 4);
    int* row_off = (int*)alloc((NN + 1) * 4);
    int* bcnt    = (int*)alloc(NBKT * 4);
    int* csr     = (int*)alloc(EE * 4);
    // bucket pairs (4.8 MB) alias h1: h1 is first written by the layer-2 k_layer,
    // long after k_fill2 has consumed bkt (stream-ordered).
    u32* bkt     = (u32*)h1;

    hipMemsetAsync(bcnt, 0, NBKT * 4, stream);

    k_bucket<<<(EE + EPB - 1) / EPB, 1024, 0, stream>>>(src, dst, bcnt, bkt);
    k_fill2<<<NBKT, 512, 0, stream>>>(bcnt, bkt, row_off, invd, csr);
    k_x2bf<<<(NN * DD / 4 + 255) / 256, 256, 0, stream>>>(x, xb);
    k_wpack<<<(3 * 4096 + 255) / 256, 256, 0, stream>>>(Ws, Wn, wpk);

    const int NB = (NN + 63) / 64;
    // layer 1: in x/xb -> h0/hb0
    k_layer<<<NB, 256, 0, stream>>>(x, xb, row_off, csr, invd,
                                    wpk + (size_t)0 * 4096 * 8,
                                    bc + 0 * DD, gm + 0 * DD, bt + 0 * DD,
                                    h0, hb0, 1);
    // layer 2: in h0/hb0 -> h1/hb1
    k_layer<<<NB, 256, 0, stream>>>(h0, hb0, row_off, csr, invd,
                                    wpk + (size_t)1 * 4096 * 8,
                                    bc + 1 * DD, gm + 1 * DD, bt + 1 * DD,
                                    h1, hb1, 1);
    // layer 3: in h1/hb1 -> emb (fp32 straight into output), no LN
    k_layer<<<NB, 256, 0, stream>>>(h1, hb1, row_off, csr, invd,
                                    wpk + (size_t)2 * 4096 * 8,
                                    bc + 2 * DD, (const float*)nullptr, (const float*)nullptr,
                                    emb, (u16*)nullptr, 0);
    k_logits<<<NB, 256, 0, stream>>>(emb, Wo, bo, out);
}